// Round 2
// baseline (143.573 us; speedup 1.0000x reference)
//
#include <hip/hip_runtime.h>
#include <hip/hip_bf16.h>

// Problem constants (B=32, N=256, K=20, channels 3->64->128->256, fc 256->128->40)
#define B_ 32
#define N_ 256
#define K_ 20
#define C1 64
#define C2 128
#define C3 256
#define F1 128
#define F2 40
#define NEG_INF (-3.402823466e38f)

// ---------------------------------------------------------------------------
// NODE 1: three independent block families:
//   blocks [0,512):     per-point MLP, 16 pts/block.
//   blocks [512,2560):  per-point top-20, one wave per point; radix-select
//                       for the 20th-largest monotone key (exact stable
//                       tie-break; output order irrelevant to gather-max).
//   blocks [2560,2576): fc1 weight transpose fc1T[n][j] = fc1w[j][n].
// ---------------------------------------------------------------------------
__global__ __launch_bounds__(256) void k_front(const float* __restrict__ x,
    const float* __restrict__ w1, const float* __restrict__ s1, const float* __restrict__ b1,
    const float* __restrict__ w2, const float* __restrict__ s2, const float* __restrict__ b2,
    const float* __restrict__ w3, const float* __restrict__ s3, const float* __restrict__ b3,
    const float* __restrict__ fc1w,
    int* __restrict__ idx, float* __restrict__ P, float* __restrict__ fc1T) {

    __shared__ float smem[3136];        // mlp only: xs 64 | y1 1024 | y2 2048
    const int blk  = blockIdx.x;
    const int t    = threadIdx.x;
    const int lane = t & 63;
    const int wv   = t >> 6;

    if (blk < 512) {
        // ================== per-point MLP, 16 points/block ==================
        float* xs = smem;               // 48 used
        float* y1 = smem + 64;          // [c1][p] 64x16
        float* y2 = smem + 1088;        // [c2][p] 128x16
        const int pbase = blk * 16;
        const int og = t >> 2;          // oc-group 0..63 (4 adjacent lanes share)
        const int p0 = (t & 3) * 4;     // pt-quad

        if (t < 48) xs[t] = x[(size_t)pbase * 3 + t];
        __syncthreads();

        // ---- layer 1: 64 x 3; thread = (oc=lane, pt-quad=wv) ----
        {
            const int oc = lane;
            const float wa = w1[oc * 3 + 0], wb = w1[oc * 3 + 1], wc = w1[oc * 3 + 2];
            const float sc = s1[oc], sh = b1[oc];
            const int q0 = wv * 4;
            float4 v;
            #pragma unroll
            for (int p = 0; p < 4; ++p) {
                const int pp = q0 + p;
                float vv = wa * xs[pp * 3 + 0] + wb * xs[pp * 3 + 1] + wc * xs[pp * 3 + 2];
                (&v.x)[p] = fmaxf(vv * sc + sh, 0.0f);
            }
            *(float4*)&y1[oc * 16 + q0] = v;
        }
        __syncthreads();

        // ---- layer 2: 128oc x 64k; thread = (2-oc group og, pt-quad) ----
        {
            const int oc0 = og * 2;
            float acc[2][4] = {};
            for (int k = 0; k < C1; k += 4) {
                float4 a[4];
                #pragma unroll
                for (int kk = 0; kk < 4; ++kk)
                    a[kk] = *(const float4*)&y1[(k + kk) * 16 + p0];
                const float4 wA = *(const float4*)(w2 + (size_t)oc0 * C1 + k);       // 4-lane dup
                const float4 wB = *(const float4*)(w2 + (size_t)(oc0 + 1) * C1 + k); // merges
                #pragma unroll
                for (int kk = 0; kk < 4; ++kk) {
                    #pragma unroll
                    for (int p = 0; p < 4; ++p) {
                        acc[0][p] += (&wA.x)[kk] * (&a[kk].x)[p];
                        acc[1][p] += (&wB.x)[kk] * (&a[kk].x)[p];
                    }
                }
            }
            const float sc0 = s2[oc0], sh0 = b2[oc0];
            const float sc1 = s2[oc0 + 1], sh1 = b2[oc0 + 1];
            float4 v0, v1;
            #pragma unroll
            for (int p = 0; p < 4; ++p) {
                (&v0.x)[p] = fmaxf(acc[0][p] * sc0 + sh0, 0.0f);
                (&v1.x)[p] = fmaxf(acc[1][p] * sc1 + sh1, 0.0f);
            }
            *(float4*)&y2[oc0 * 16 + p0]       = v0;
            *(float4*)&y2[(oc0 + 1) * 16 + p0] = v1;
        }
        __syncthreads();

        // ---- layer 3: 256oc x 128k; thread = (4-oc group og, pt-quad) ----
        {
            const int oc0 = og * 4;
            float acc[4][4] = {};
            for (int k = 0; k < C2; k += 4) {
                float4 a[4];
                #pragma unroll
                for (int kk = 0; kk < 4; ++kk)
                    a[kk] = *(const float4*)&y2[(k + kk) * 16 + p0];
                float4 w[4];
                #pragma unroll
                for (int o = 0; o < 4; ++o)
                    w[o] = *(const float4*)(w3 + (size_t)(oc0 + o) * C2 + k);        // 4-lane dup
                #pragma unroll
                for (int o = 0; o < 4; ++o) {
                    #pragma unroll
                    for (int kk = 0; kk < 4; ++kk) {
                        const float wvv = (&w[o].x)[kk];
                        #pragma unroll
                        for (int p = 0; p < 4; ++p)
                            acc[o][p] += wvv * (&a[kk].x)[p];
                    }
                }
            }
            const float4 sc = *(const float4*)&s3[oc0];
            const float4 sh = *(const float4*)&b3[oc0];
            #pragma unroll
            for (int p = 0; p < 4; ++p) {
                float4 v;
                #pragma unroll
                for (int o = 0; o < 4; ++o)
                    (&v.x)[o] = fmaxf(acc[o][p] * (&sc.x)[o] + (&sh.x)[o], 0.0f);
                *(float4*)&P[(size_t)(pbase + p0 + p) * C3 + oc0] = v;
            }
        }

    } else if (blk < 2560) {
        // ================== top-20, one wave per point, LDS-free ==================
        const int tb = blk - 512;
        const int b  = tb >> 6;
        const int n  = ((tb & 63) << 2) | wv;
        const int bn = (b << 8) | n;
        const float* xb = x + (size_t)b * N_ * 3;

        const float nx = xb[n * 3 + 0], ny = xb[n * 3 + 1], nz = xb[n * 3 + 2];
        const float xxn = nx * nx + ny * ny + nz * nz;

        unsigned k0, k1, k2, k3;
        {
            unsigned kk[4];
            #pragma unroll
            for (int i = 0; i < 4; ++i) {
                const int m = lane + (i << 6);
                const float cx = xb[m * 3 + 0], cy = xb[m * 3 + 1], cz = xb[m * 3 + 2];
                const float xxm = cx * cx + cy * cy + cz * cz;
                const float v = 2.0f * (nx * cx + ny * cy + nz * cz) - xxn - xxm;
                const unsigned u = __float_as_uint(v);
                kk[i] = (u & 0x80000000u) ? ~u : (u | 0x80000000u);   // monotone
            }
            k0 = kk[0]; k1 = kk[1]; k2 = kk[2]; k3 = kk[3];
        }
        // Self point: v == +0.0 exactly -> key 0x80000000, strict max; bit 31
        // of T is provably 0, so the bit-31 step is skipped.

        unsigned prefix = 0u;
        #pragma unroll
        for (int bit = 30; bit >= 0; --bit) {
            const unsigned cand = prefix | (1u << bit);
            const int c = __popcll(__ballot(k0 >= cand))
                        + __popcll(__ballot(k1 >= cand))
                        + __popcll(__ballot(k2 >= cand))
                        + __popcll(__ballot(k3 >= cand));
            if (c >= K_) prefix = cand;
        }
        const unsigned T = prefix;          // count(>=T) >= 20, count(>T) < 20

        int* op = idx + (size_t)bn * K_;
        const unsigned long long lt = (1ull << lane) - 1ull;

        const unsigned long long G0 = __ballot(k0 > T);
        const unsigned long long G1 = __ballot(k1 > T);
        const unsigned long long G2 = __ballot(k2 > T);
        const unsigned long long G3 = __ballot(k3 > T);
        const int n0 = __popcll(G0), n1 = __popcll(G1), n2 = __popcll(G2), n3 = __popcll(G3);
        const int g = n0 + n1 + n2 + n3;
        if (k0 > T) op[          __popcll(G0 & lt)] = lane;
        if (k1 > T) op[n0      + __popcll(G1 & lt)] = 64  | lane;
        if (k2 > T) op[n0 + n1 + __popcll(G2 & lt)] = 128 | lane;
        if (k3 > T) op[n0 + n1 + n2 + __popcll(G3 & lt)] = 192 | lane;

        const int e = K_ - g;               // >= 1 by maximality of T
        const unsigned long long E0 = __ballot(k0 == T);
        const unsigned long long E1 = __ballot(k1 == T);
        const unsigned long long E2 = __ballot(k2 == T);
        const unsigned long long E3 = __ballot(k3 == T);
        const int m0 = __popcll(E0), m1 = __popcll(E1), m2 = __popcll(E2);
        if (k0 == T) { const int p = __popcll(E0 & lt);                 if (p < e) op[g + p] = lane; }
        if (k1 == T) { const int p = m0 + __popcll(E1 & lt);            if (p < e) op[g + p] = 64  | lane; }
        if (k2 == T) { const int p = m0 + m1 + __popcll(E2 & lt);       if (p < e) op[g + p] = 128 | lane; }
        if (k3 == T) { const int p = m0 + m1 + m2 + __popcll(E3 & lt);  if (p < e) op[g + p] = 192 | lane; }

    } else {
        // ================== fc1 weight transpose ==================
        const int g = (blk - 2560) * 256 + t;   // 0..4095
        #pragma unroll
        for (int i = 0; i < 8; ++i) {           // 32768 elems
            const int e = g + i * 4096;
            const int j = e >> 8, nn = e & 255;
            fc1T[nn * F1 + j] = fc1w[e];
        }
    }
}

// ---------------------------------------------------------------------------
// NODE 2: FUSED gather-max + fc1(relu) + fc2.
// R2: 512 threads/block (8 waves) instead of 256 -> 16 waves/CU = 4/SIMD
// (was 2/SIMD), doubling latency tolerance for stage A's dependent
// idx->gather load chain. All arithmetic orders preserved (bitwise-identical
// output): every fc1 (j,ci) still accumulates n=0..255 sequentially in one
// thread; gather-max keeps the same j-order; stage C unchanged on waves 0-3.
// ---------------------------------------------------------------------------
#define GLT_S 20                        // glT row stride (words), %4==0 for b128
__global__ __launch_bounds__(512) void k_gfc(const float* __restrict__ P,
                                             const int* __restrict__ idx,
                                             const float* __restrict__ fc1T,
                                             const float* __restrict__ fc1b,
                                             const float* __restrict__ fc2w,
                                             const float* __restrict__ fc2b,
                                             float* __restrict__ out) {
    const int b    = blockIdx.x >> 4;
    const int ch0  = (blockIdx.x & 15) * 16;
    const int t    = threadIdx.x;
    const int lane = t & 63;

    __shared__ float Ht[N_ * 16];       // [n][ci], 16 KB
    __shared__ float glT[F1 * GLT_S];   // [j][ci], 10.2 KB
    __shared__ float w2l[F2 * 129];     // [m][j], padded (129 = 1 mod 32)

    for (int e = t; e < F2 * F1; e += 512)
        w2l[(e >> 7) * 129 + (e & 127)] = fc2w[e];

    // ---- stage A: gather-max into Ht (2 row-passes of 128 n) ----
    {
        const int q  = t & 3;           // ch-quad
        const int nl = t >> 2;          // n within half-pass, 0..127
        const float* Pq = P + (size_t)b * N_ * C3 + ch0 + q * 4;
        #pragma unroll
        for (int r = 0; r < 2; ++r) {
            const int n = r * 128 + nl;
            const int* ib = idx + ((size_t)((b << 8) | n)) * K_;
            float4 m = make_float4(NEG_INF, NEG_INF, NEG_INF, NEG_INF);
            #pragma unroll
            for (int j = 0; j < K_; ++j) {
                const int id = ib[j];
                const float4 p = *(const float4*)(Pq + (size_t)id * C3);
                m.x = fmaxf(m.x, p.x);
                m.y = fmaxf(m.y, p.y);
                m.z = fmaxf(m.z, p.z);
                m.w = fmaxf(m.w, p.w);
            }
            *(float4*)&Ht[n * 16 + q * 4] = m;
        }
    }
    __syncthreads();

    // ---- stage B: fc1 + relu -> glT[j][ci]; wave = ch-pair, lane = j-pair ----
    {
        const int c0 = (t >> 6) * 2;    // wave's ch-pair (8 waves x 2 ch)
        float acc[2][2] = {};
        #pragma unroll 4
        for (int n = 0; n < N_; ++n) {
            const float2 w = *(const float2*)&fc1T[n * F1 + lane * 2];  // coalesced
            const float2 a = *(const float2*)&Ht[n * 16 + c0];          // broadcast
            acc[0][0] += w.x * a.x;  acc[0][1] += w.x * a.y;
            acc[1][0] += w.y * a.x;  acc[1][1] += w.y * a.y;
        }
        const float bb0 = fc1b[lane * 2], bb1 = fc1b[lane * 2 + 1];
        float2 va, vb;
        va.x = fmaxf(acc[0][0] + bb0, 0.0f);
        va.y = fmaxf(acc[0][1] + bb0, 0.0f);
        vb.x = fmaxf(acc[1][0] + bb1, 0.0f);
        vb.y = fmaxf(acc[1][1] + bb1, 0.0f);
        // rows j = 2*lane, 2*lane+1; this wave owns columns c0, c0+1
        *(float2*)&glT[(lane * 2)     * GLT_S + c0] = va;
        *(float2*)&glT[(lane * 2 + 1) * GLT_S + c0] = vb;
    }
    __syncthreads();

    // ---- stage C: fc2 -> out. waves 0-3: wave = ci-quad, lane = m (40/64) ----
    if (t < 256) {
        const int m   = t & 63;
        const int cig = t >> 6;         // 0..3 -> ci = cig*4 .. cig*4+3
        if (m < F2) {
            float a0 = 0.f, a1 = 0.f, a2 = 0.f, a3 = 0.f;
            const float* wr = w2l + m * 129;        // per-lane row, ~2-way banks
            const float* gp = glT + cig * 4;        // wave-uniform -> broadcast
            #pragma unroll 4
            for (int j = 0; j < F1; ++j) {
                const float w = wr[j];
                const float4 gv = *(const float4*)(gp + j * GLT_S);
                a0 += w * gv.x;
                a1 += w * gv.y;
                a2 += w * gv.z;
                a3 += w * gv.w;
            }
            const float bb = fc2b[m];
            const size_t rb = (size_t)(b * C3 + ch0 + cig * 4) * F2 + m;
            out[rb]          = a0 + bb;
            out[rb + F2]     = a1 + bb;
            out[rb + 2 * F2] = a2 + bb;
            out[rb + 3 * F2] = a3 + bb;
        }
    }
}

// ---------------------------------------------------------------------------
extern "C" void kernel_launch(void* const* d_in, const int* in_sizes, int n_in,
                              void* d_out, int out_size, void* d_ws, size_t ws_size,
                              hipStream_t stream) {
    const float* x    = (const float*)d_in[0];
    const float* w1   = (const float*)d_in[1];
    const float* s1   = (const float*)d_in[2];
    const float* t1   = (const float*)d_in[3];
    const float* w2   = (const float*)d_in[4];
    const float* s2   = (const float*)d_in[5];
    const float* t2   = (const float*)d_in[6];
    const float* w3   = (const float*)d_in[7];
    const float* s3   = (const float*)d_in[8];
    const float* t3   = (const float*)d_in[9];
    const float* fc1w = (const float*)d_in[10];
    const float* fc1b = (const float*)d_in[11];
    const float* fc2w = (const float*)d_in[12];
    const float* fc2b = (const float*)d_in[13];
    float* out = (float*)d_out;

    // Workspace layout (all fully overwritten every call):
    char* ws = (char*)d_ws;
    int*   idx  = (int*)ws;                                  // 655,360 B
    float* P    = (float*)(ws + (size_t)B_ * N_ * K_ * 4);   // 8 MB
    float* fc1T = P + (size_t)B_ * N_ * C3;                  // 131,072 B

    k_front<<<2576, 256, 0, stream>>>(x, w1, s1, t1, w2, s2, t2, w3, s3, t3,
                                      fc1w, idx, P, fc1T);
    k_gfc<<<B_ * 16, 512, 0, stream>>>(P, idx, fc1T, fc1b, fc2w, fc2b, out);
}

// Round 3
// 123.352 us; speedup vs baseline: 1.1639x; 1.1639x over previous
//
#include <hip/hip_runtime.h>
#include <hip/hip_bf16.h>

// Problem constants (B=32, N=256, K=20, channels 3->64->128->256, fc 256->128->40)
#define B_ 32
#define N_ 256
#define K_ 20
#define C1 64
#define C2 128
#define C3 256
#define F1 128
#define F2 40
#define NEG_INF (-3.402823466e38f)

// ---------------------------------------------------------------------------
// NODE 1: three independent block families:
//   blocks [0,512):     per-point MLP, 16 pts/block.
//   blocks [512,2560):  per-point top-20, one wave per point; radix-select
//                       for the 20th-largest monotone key (exact stable
//                       tie-break; output order irrelevant to gather-max).
//   blocks [2560,2576): fc1 weight transpose fc1T[n][j] = fc1w[j][n].
// ---------------------------------------------------------------------------
__global__ __launch_bounds__(256) void k_front(const float* __restrict__ x,
    const float* __restrict__ w1, const float* __restrict__ s1, const float* __restrict__ b1,
    const float* __restrict__ w2, const float* __restrict__ s2, const float* __restrict__ b2,
    const float* __restrict__ w3, const float* __restrict__ s3, const float* __restrict__ b3,
    const float* __restrict__ fc1w,
    int* __restrict__ idx, float* __restrict__ P, float* __restrict__ fc1T) {

    __shared__ float smem[3136];        // mlp only: xs 64 | y1 1024 | y2 2048
    const int blk  = blockIdx.x;
    const int t    = threadIdx.x;
    const int lane = t & 63;
    const int wv   = t >> 6;

    if (blk < 512) {
        // ================== per-point MLP, 16 points/block ==================
        float* xs = smem;               // 48 used
        float* y1 = smem + 64;          // [c1][p] 64x16
        float* y2 = smem + 1088;        // [c2][p] 128x16
        const int pbase = blk * 16;
        const int og = t >> 2;          // oc-group 0..63 (4 adjacent lanes share)
        const int p0 = (t & 3) * 4;     // pt-quad

        if (t < 48) xs[t] = x[(size_t)pbase * 3 + t];
        __syncthreads();

        // ---- layer 1: 64 x 3; thread = (oc=lane, pt-quad=wv) ----
        {
            const int oc = lane;
            const float wa = w1[oc * 3 + 0], wb = w1[oc * 3 + 1], wc = w1[oc * 3 + 2];
            const float sc = s1[oc], sh = b1[oc];
            const int q0 = wv * 4;
            float4 v;
            #pragma unroll
            for (int p = 0; p < 4; ++p) {
                const int pp = q0 + p;
                float vv = wa * xs[pp * 3 + 0] + wb * xs[pp * 3 + 1] + wc * xs[pp * 3 + 2];
                (&v.x)[p] = fmaxf(vv * sc + sh, 0.0f);
            }
            *(float4*)&y1[oc * 16 + q0] = v;
        }
        __syncthreads();

        // ---- layer 2: 128oc x 64k; thread = (2-oc group og, pt-quad) ----
        {
            const int oc0 = og * 2;
            float acc[2][4] = {};
            for (int k = 0; k < C1; k += 4) {
                float4 a[4];
                #pragma unroll
                for (int kk = 0; kk < 4; ++kk)
                    a[kk] = *(const float4*)&y1[(k + kk) * 16 + p0];
                const float4 wA = *(const float4*)(w2 + (size_t)oc0 * C1 + k);       // 4-lane dup
                const float4 wB = *(const float4*)(w2 + (size_t)(oc0 + 1) * C1 + k); // merges
                #pragma unroll
                for (int kk = 0; kk < 4; ++kk) {
                    #pragma unroll
                    for (int p = 0; p < 4; ++p) {
                        acc[0][p] += (&wA.x)[kk] * (&a[kk].x)[p];
                        acc[1][p] += (&wB.x)[kk] * (&a[kk].x)[p];
                    }
                }
            }
            const float sc0 = s2[oc0], sh0 = b2[oc0];
            const float sc1 = s2[oc0 + 1], sh1 = b2[oc0 + 1];
            float4 v0, v1;
            #pragma unroll
            for (int p = 0; p < 4; ++p) {
                (&v0.x)[p] = fmaxf(acc[0][p] * sc0 + sh0, 0.0f);
                (&v1.x)[p] = fmaxf(acc[1][p] * sc1 + sh1, 0.0f);
            }
            *(float4*)&y2[oc0 * 16 + p0]       = v0;
            *(float4*)&y2[(oc0 + 1) * 16 + p0] = v1;
        }
        __syncthreads();

        // ---- layer 3: 256oc x 128k; thread = (4-oc group og, pt-quad) ----
        {
            const int oc0 = og * 4;
            float acc[4][4] = {};
            for (int k = 0; k < C2; k += 4) {
                float4 a[4];
                #pragma unroll
                for (int kk = 0; kk < 4; ++kk)
                    a[kk] = *(const float4*)&y2[(k + kk) * 16 + p0];
                float4 w[4];
                #pragma unroll
                for (int o = 0; o < 4; ++o)
                    w[o] = *(const float4*)(w3 + (size_t)(oc0 + o) * C2 + k);        // 4-lane dup
                #pragma unroll
                for (int o = 0; o < 4; ++o) {
                    #pragma unroll
                    for (int kk = 0; kk < 4; ++kk) {
                        const float wvv = (&w[o].x)[kk];
                        #pragma unroll
                        for (int p = 0; p < 4; ++p)
                            acc[o][p] += wvv * (&a[kk].x)[p];
                    }
                }
            }
            const float4 sc = *(const float4*)&s3[oc0];
            const float4 sh = *(const float4*)&b3[oc0];
            #pragma unroll
            for (int p = 0; p < 4; ++p) {
                float4 v;
                #pragma unroll
                for (int o = 0; o < 4; ++o)
                    (&v.x)[o] = fmaxf(acc[o][p] * (&sc.x)[o] + (&sh.x)[o], 0.0f);
                *(float4*)&P[(size_t)(pbase + p0 + p) * C3 + oc0] = v;
            }
        }

    } else if (blk < 2560) {
        // ================== top-20, one wave per point, LDS-free ==================
        const int tb = blk - 512;
        const int b  = tb >> 6;
        const int n  = ((tb & 63) << 2) | wv;
        const int bn = (b << 8) | n;
        const float* xb = x + (size_t)b * N_ * 3;

        const float nx = xb[n * 3 + 0], ny = xb[n * 3 + 1], nz = xb[n * 3 + 2];
        const float xxn = nx * nx + ny * ny + nz * nz;

        unsigned k0, k1, k2, k3;
        {
            unsigned kk[4];
            #pragma unroll
            for (int i = 0; i < 4; ++i) {
                const int m = lane + (i << 6);
                const float cx = xb[m * 3 + 0], cy = xb[m * 3 + 1], cz = xb[m * 3 + 2];
                const float xxm = cx * cx + cy * cy + cz * cz;
                const float v = 2.0f * (nx * cx + ny * cy + nz * cz) - xxn - xxm;
                const unsigned u = __float_as_uint(v);
                kk[i] = (u & 0x80000000u) ? ~u : (u | 0x80000000u);   // monotone
            }
            k0 = kk[0]; k1 = kk[1]; k2 = kk[2]; k3 = kk[3];
        }
        // Self point: v == +0.0 exactly -> key 0x80000000, strict max; bit 31
        // of T is provably 0, so the bit-31 step is skipped.

        unsigned prefix = 0u;
        #pragma unroll
        for (int bit = 30; bit >= 0; --bit) {
            const unsigned cand = prefix | (1u << bit);
            const int c = __popcll(__ballot(k0 >= cand))
                        + __popcll(__ballot(k1 >= cand))
                        + __popcll(__ballot(k2 >= cand))
                        + __popcll(__ballot(k3 >= cand));
            if (c >= K_) prefix = cand;
        }
        const unsigned T = prefix;          // count(>=T) >= 20, count(>T) < 20

        int* op = idx + (size_t)bn * K_;
        const unsigned long long lt = (1ull << lane) - 1ull;

        const unsigned long long G0 = __ballot(k0 > T);
        const unsigned long long G1 = __ballot(k1 > T);
        const unsigned long long G2 = __ballot(k2 > T);
        const unsigned long long G3 = __ballot(k3 > T);
        const int n0 = __popcll(G0), n1 = __popcll(G1), n2 = __popcll(G2), n3 = __popcll(G3);
        const int g = n0 + n1 + n2 + n3;
        if (k0 > T) op[          __popcll(G0 & lt)] = lane;
        if (k1 > T) op[n0      + __popcll(G1 & lt)] = 64  | lane;
        if (k2 > T) op[n0 + n1 + __popcll(G2 & lt)] = 128 | lane;
        if (k3 > T) op[n0 + n1 + n2 + __popcll(G3 & lt)] = 192 | lane;

        const int e = K_ - g;               // >= 1 by maximality of T
        const unsigned long long E0 = __ballot(k0 == T);
        const unsigned long long E1 = __ballot(k1 == T);
        const unsigned long long E2 = __ballot(k2 == T);
        const unsigned long long E3 = __ballot(k3 == T);
        const int m0 = __popcll(E0), m1 = __popcll(E1), m2 = __popcll(E2);
        if (k0 == T) { const int p = __popcll(E0 & lt);                 if (p < e) op[g + p] = lane; }
        if (k1 == T) { const int p = m0 + __popcll(E1 & lt);            if (p < e) op[g + p] = 64  | lane; }
        if (k2 == T) { const int p = m0 + m1 + __popcll(E2 & lt);       if (p < e) op[g + p] = 128 | lane; }
        if (k3 == T) { const int p = m0 + m1 + m2 + __popcll(E3 & lt);  if (p < e) op[g + p] = 192 | lane; }

    } else {
        // ================== fc1 weight transpose ==================
        const int g = (blk - 2560) * 256 + t;   // 0..4095
        #pragma unroll
        for (int i = 0; i < 8; ++i) {           // 32768 elems
            const int e = g + i * 4096;
            const int j = e >> 8, nn = e & 255;
            fc1T[nn * F1 + j] = fc1w[e];
        }
    }
}

// ---------------------------------------------------------------------------
// NODE 2: FUSED gather-max + fc1(relu) + fc2.
// R3: back to 256 threads (R2's 512-thr regressed: redundant per-wave fc1T
// streaming doubled). New: stage B stages fc1T in LDS tiles (4 x 64rows x
// 128j = 32 KB), loaded once per block coalesced -> cuts the 4x per-wave
// redundant global streaming of fc1T to 1x per block. Accumulation order per
// (j,ci) remains exactly n=0..255 sequential (bitwise-identical output).
// w2l (fc2 weights, same [m][j] 129-stride layout as before) is now loaded
// AFTER stage B into the then-dead Ht/ftile LDS region.
// ---------------------------------------------------------------------------
#define GLT_S 20                        // glT row stride (words), %4==0 for b128
__global__ __launch_bounds__(256) void k_gfc(const float* __restrict__ P,
                                             const int* __restrict__ idx,
                                             const float* __restrict__ fc1T,
                                             const float* __restrict__ fc1b,
                                             const float* __restrict__ fc2w,
                                             const float* __restrict__ fc2b,
                                             float* __restrict__ out) {
    const int b    = blockIdx.x >> 4;
    const int ch0  = (blockIdx.x & 15) * 16;
    const int t    = threadIdx.x;
    const int lane = t & 63;

    __shared__ float smem[14848];       // 59.4 KB
    float* Ht    = smem;                // [n][ci] 256x16 (16 KB), dead after B
    float* ftile = smem + 4096;         // [64][128] fc1T tile (32 KB), dead after B
    float* glT   = smem + 12288;        // [j][ci] 128x20 (10.25 KB)
    float* w2l   = smem;                // [m][j] 40x129, aliases Ht/ftile post-B

    // ---- stage A: gather-max into Ht ----
    {
        const int q  = t & 3;           // ch-quad
        const int nl = t >> 2;          // n within quarter-pass
        const float* Pq = P + (size_t)b * N_ * C3 + ch0 + q * 4;
        #pragma unroll
        for (int r = 0; r < 4; ++r) {
            const int n = r * 64 + nl;
            const int* ib = idx + ((size_t)((b << 8) | n)) * K_;
            float4 m = make_float4(NEG_INF, NEG_INF, NEG_INF, NEG_INF);
            #pragma unroll
            for (int j = 0; j < K_; ++j) {
                const int id = ib[j];
                const float4 p = *(const float4*)(Pq + (size_t)id * C3);
                m.x = fmaxf(m.x, p.x);
                m.y = fmaxf(m.y, p.y);
                m.z = fmaxf(m.z, p.z);
                m.w = fmaxf(m.w, p.w);
            }
            *(float4*)&Ht[n * 16 + q * 4] = m;
        }
    }
    __syncthreads();

    // ---- stage B: fc1 + relu -> glT[j][ci]; fc1T LDS-tiled ----
    {
        const int c0 = (t >> 6) * 4;    // wave's ch-quad
        float acc[2][4] = {};
        for (int nt = 0; nt < 4; ++nt) {
            // cooperative coalesced tile load: rows nt*64 .. nt*64+63
            {
                const float4* src = (const float4*)(fc1T + (size_t)nt * 64 * F1);
                float4* dst = (float4*)ftile;
                #pragma unroll
                for (int i = 0; i < 8; ++i)
                    dst[t + i * 256] = src[t + i * 256];
            }
            __syncthreads();
            #pragma unroll 4
            for (int nn = 0; nn < 64; ++nn) {
                const int n = nt * 64 + nn;
                const float2 w = *(const float2*)&ftile[nn * F1 + lane * 2]; // 2-way banks
                const float4 a = *(const float4*)&Ht[n * 16 + c0];           // broadcast
                #pragma unroll
                for (int c = 0; c < 4; ++c) {
                    acc[0][c] += w.x * (&a.x)[c];
                    acc[1][c] += w.y * (&a.x)[c];
                }
            }
            __syncthreads();            // ftile dead before next overwrite
        }
        const float bb0 = fc1b[lane * 2], bb1 = fc1b[lane * 2 + 1];
        float4 va, vb;
        #pragma unroll
        for (int c = 0; c < 4; ++c) {
            (&va.x)[c] = fmaxf(acc[0][c] + bb0, 0.0f);
            (&vb.x)[c] = fmaxf(acc[1][c] + bb1, 0.0f);
        }
        // rows j = 2*lane, 2*lane+1; this wave owns columns c0..c0+3
        *(float4*)&glT[(lane * 2)     * GLT_S + c0] = va;
        *(float4*)&glT[(lane * 2 + 1) * GLT_S + c0] = vb;
    }
    // Ht/ftile are dead (trailing barrier of tile loop passed) -> fill w2l.
    for (int e = t; e < F2 * F1; e += 256)
        w2l[(e >> 7) * 129 + (e & 127)] = fc2w[e];
    __syncthreads();

    // ---- stage C: fc2 -> out. wave = ci-quad (cig), lane = m (40 of 64) ----
    {
        const int m   = t & 63;
        const int cig = t >> 6;         // 0..3 -> ci = cig*4 .. cig*4+3
        if (m < F2) {
            float a0 = 0.f, a1 = 0.f, a2 = 0.f, a3 = 0.f;
            const float* wr = w2l + m * 129;        // per-lane row, ~2-way banks
            const float* gp = glT + cig * 4;        // wave-uniform -> broadcast
            #pragma unroll 4
            for (int j = 0; j < F1; ++j) {
                const float w = wr[j];
                const float4 gv = *(const float4*)(gp + j * GLT_S);
                a0 += w * gv.x;
                a1 += w * gv.y;
                a2 += w * gv.z;
                a3 += w * gv.w;
            }
            const float bb = fc2b[m];
            const size_t rb = (size_t)(b * C3 + ch0 + cig * 4) * F2 + m;
            out[rb]          = a0 + bb;
            out[rb + F2]     = a1 + bb;
            out[rb + 2 * F2] = a2 + bb;
            out[rb + 3 * F2] = a3 + bb;
        }
    }
}

// ---------------------------------------------------------------------------
extern "C" void kernel_launch(void* const* d_in, const int* in_sizes, int n_in,
                              void* d_out, int out_size, void* d_ws, size_t ws_size,
                              hipStream_t stream) {
    const float* x    = (const float*)d_in[0];
    const float* w1   = (const float*)d_in[1];
    const float* s1   = (const float*)d_in[2];
    const float* t1   = (const float*)d_in[3];
    const float* w2   = (const float*)d_in[4];
    const float* s2   = (const float*)d_in[5];
    const float* t2   = (const float*)d_in[6];
    const float* w3   = (const float*)d_in[7];
    const float* s3   = (const float*)d_in[8];
    const float* t3   = (const float*)d_in[9];
    const float* fc1w = (const float*)d_in[10];
    const float* fc1b = (const float*)d_in[11];
    const float* fc2w = (const float*)d_in[12];
    const float* fc2b = (const float*)d_in[13];
    float* out = (float*)d_out;

    // Workspace layout (all fully overwritten every call):
    char* ws = (char*)d_ws;
    int*   idx  = (int*)ws;                                  // 655,360 B
    float* P    = (float*)(ws + (size_t)B_ * N_ * K_ * 4);   // 8 MB
    float* fc1T = P + (size_t)B_ * N_ * C3;                  // 131,072 B

    k_front<<<2576, 256, 0, stream>>>(x, w1, s1, t1, w2, s2, t2, w3, s3, t3,
                                      fc1w, idx, P, fc1T);
    k_gfc<<<B_ * 16, 256, 0, stream>>>(P, idx, fc1T, fc1b, fc2w, fc2b, out);
}